// Round 9
// baseline (37.891 us; speedup 1.0000x reference)
//
#include <hip/hip_runtime.h>
#include <math.h>

// OrthogonalButterfly: X (1024 x 8192) fp32, 20 butterfly layers, stride 2^(l%10).
// R8 = 36.8us (best): 512 thr = 8 float2-cols x 64 subs, y=float2[16], LDS 64KB,
// 4-transpose/7-barrier schedule, involution swizzle. Traffic ideal, no spill.
// Remaining cost: exposed table-load latency on the serial 20-layer chain
// (all pipes <25%, ~2 blocks/CU).
// R9: fully-unrolled 1-layer-lookahead table prefetch with ping-pong register
// buffers qa/qb (4x float4 each; no per-layer copies). PREFs cross barriers so
// loads stay in flight through the transpose. +32 VGPR (~115 total, <=128 ->
// still 4 waves/SIMD). Geometry/schedule/swizzle byte-identical to R8.
//
// Phase row maps (sub in [0,64), i in [0,16)):
//   P1: r = sub<<4 | i                          layers s=1,2,4,8     (SL=1,2,4,8)
//   P2: r = (sub&15) | i<<4 | (sub>>4)<<8       layers s=16..128     (SL=1,2,4,8)
//   P3: r = (i&3) | sub<<2 | (i>>2)<<8          layers s=256,512,1,2 (SL=4,8,1,2)
//   P4: r = (sub&3) | (i&3)<<2 | ((i>>2)&3)<<4 | (sub>>2)<<6
//                                               layers s=4..32       (SL=1,2,4,8)
//   P5: r = sub | (i&3)<<6 | (i>>2)<<8          layers s=64..512     (SL=1,2,4,8)

#define NROW   1024
#define BATCH  8192
#define BATCH2 (BATCH / 2)
#define DEPTH  20
#define NANG   512
#define TAB_ELEMS (DEPTH * NANG)
#define TAB_BYTES ((size_t)TAB_ELEMS * 8)

__device__ __host__ __forceinline__ int rowP1(int sub, int i){ return (sub<<4)|i; }
__device__ __host__ __forceinline__ int rowP2(int sub, int i){ return (sub&15) | (i<<4) | ((sub>>4)<<8); }
__device__ __host__ __forceinline__ int rowP3(int sub, int i){ return (i&3) | (sub<<2) | ((i>>2)<<8); }
__device__ __host__ __forceinline__ int rowP4(int sub, int i){ return (sub&3) | ((i&3)<<2) | (((i>>2)&3)<<4) | ((sub>>2)<<6); }
__device__ __host__ __forceinline__ int rowP5(int sub, int i){ return sub | ((i&3)<<6) | ((i>>2)<<8); }

// ---------------- angle table build (identical to R6/R7/R8, verified) ----------------
__global__ void build_tab_kernel(const float* __restrict__ ang,
                                 float2* __restrict__ tab) {
    int idx = blockIdx.x * blockDim.x + threadIdx.x;
    if (idx >= TAB_ELEMS) return;
    int l = idx >> 9;
    int slot = idx & (NANG - 1);
    int sub = slot >> 3, p = slot & 7;
    int sp = l % 10;
    int SL, ph;
    if (l < 4)       { ph = 0; SL = 1 << l; }
    else if (l < 8)  { ph = 1; SL = 1 << (l - 4); }
    else if (l < 12) { ph = 2; SL = (l == 8) ? 4 : (l == 9) ? 8 : (l == 10) ? 1 : 2; }
    else if (l < 16) { ph = 3; SL = 1 << (l - 12); }
    else             { ph = 4; SL = 1 << (l - 16); }
    int i0 = 2 * (p / SL) * SL + p % SL;
    int r;
    if (ph == 0)      r = rowP1(sub, i0);
    else if (ph == 1) r = rowP2(sub, i0);
    else if (ph == 2) r = rowP3(sub, i0);
    else if (ph == 3) r = rowP4(sub, i0);
    else              r = rowP5(sub, i0);
    int s = 1 << sp;
    int a = ((r >> (sp + 1)) << sp) | (r & (s - 1));
    float th = ang[l * NANG + a];
    float sv, cv;
    sincosf(th, &sv, &cv);
    tab[idx] = make_float2(cv, sv);
}

// ---------------- main kernel ----------------
__device__ __forceinline__ void rot2(float2& a, float2& b, float cv, float sv) {
    float2 x0 = a, x1 = b;
    a.x = cv * x0.x + sv * x1.x;  b.x = cv * x1.x - sv * x0.x;
    a.y = cv * x0.y + sv * x1.y;  b.y = cv * x1.y - sv * x0.y;
}

// Apply one layer from a 4-float4 register slice (8 cos/sin pairs).
template<int SL>
__device__ __forceinline__ void apply(float2 y[16], const float4 q[4]) {
    #pragma unroll
    for (int v = 0; v < 4; ++v) {
        float4 qq = q[v];
        int p0 = 2 * v, p1 = 2 * v + 1;
        int a0 = 2 * (p0 / SL) * SL + p0 % SL;   // constant-folds
        int a1 = 2 * (p1 / SL) * SL + p1 % SL;
        rot2(y[a0], y[a0 + SL], qq.x, qq.y);
        rot2(y[a1], y[a1 + SL], qq.z, qq.w);
    }
}

// Prefetch layer l's 64B slice for this sub into 4 float4 regs.
__device__ __forceinline__ void pref(float4 q[4], const float4* __restrict__ tf4,
                                     int l, int sub) {
    const float4* s = tf4 + l * (NANG / 2) + 4 * sub;
    q[0] = s[0]; q[1] = s[1]; q[2] = s[2]; q[3] = s[3];
}

// Fallback without workspace: inline sincos (angles shared by the 2 cols).
template<int SL, int PH, int SP>
__device__ __forceinline__ void layer_notab(float2 y[16],
                                            const float* __restrict__ angL,
                                            int sub) {
    #pragma unroll
    for (int p = 0; p < 8; ++p) {
        int i0 = 2 * (p / SL) * SL + p % SL;
        int r;
        if (PH == 0)      r = rowP1(sub, i0);
        else if (PH == 1) r = rowP2(sub, i0);
        else if (PH == 2) r = rowP3(sub, i0);
        else if (PH == 3) r = rowP4(sub, i0);
        else              r = rowP5(sub, i0);
        int a = ((r >> (SP + 1)) << SP) | (r & ((1 << SP) - 1));
        float th = angL[a];
        float sv, cv;
        __sincosf(th, &sv, &cv);
        rot2(y[i0], y[i0 + SL], cv, sv);
    }
}

// LDS element address for (float2-col c, row r). sigma involution pushes sub
// bits into the bank index on all phase maps; c<<1 decorrelates columns.
__device__ __forceinline__ int eaddr(int c, int r) {
    return (c << 10) | ((r ^ ((r >> 4) & 15)) ^ (c << 1));
}

template<bool USE_TAB>
__global__ __launch_bounds__(512) void butterfly_kernel(
        const float* __restrict__ X, const float* __restrict__ ang,
        const float2* __restrict__ tab, float* __restrict__ out) {
    __shared__ float2 lds2[8 * 1024];    // 64 KB -> 2 blocks/CU
    int t = threadIdx.x;
    int c = t & 7;                       // float2-column within block
    int sub = t >> 3;                    // [0,64)
    int bid = blockIdx.x;
    int L = ((bid & 7) << 6) | (bid >> 3);   // XCD-aware, bijective (512 = 8*64)
    int col2 = (L << 3) + c;             // float2-col in [0,4096)

    float2 y[16];
    const float2* Xp = reinterpret_cast<const float2*>(X) + col2;

    if (USE_TAB) {
        const float4* tf4 = reinterpret_cast<const float4*>(tab);
        float4 qa[4], qb[4];
        pref(qa, tf4, 0, sub);                       // before X loads
        #pragma unroll
        for (int i = 0; i < 16; ++i)
            y[i] = Xp[rowP1(sub, i) * BATCH2];

        // P1: s=1,2,4,8
        pref(qb, tf4, 1, sub);  apply<1>(y, qa);
        pref(qa, tf4, 2, sub);  apply<2>(y, qb);
        pref(qb, tf4, 3, sub);  apply<4>(y, qa);
        pref(qa, tf4, 4, sub);  apply<8>(y, qb);     // layer4 pref crosses T1
        // T1: wr P1 / rd P2
        #pragma unroll
        for (int i = 0; i < 16; ++i) lds2[eaddr(c, rowP1(sub, i))] = y[i];
        __syncthreads();
        #pragma unroll
        for (int i = 0; i < 16; ++i) y[i] = lds2[eaddr(c, rowP2(sub, i))];
        // P2: s=16,32,64,128
        pref(qb, tf4, 5, sub);  apply<1>(y, qa);
        pref(qa, tf4, 6, sub);  apply<2>(y, qb);
        pref(qb, tf4, 7, sub);  apply<4>(y, qa);
        pref(qa, tf4, 8, sub);  apply<8>(y, qb);     // layer8 pref crosses T2
        // T2: wr P2 / rd P3
        __syncthreads();
        #pragma unroll
        for (int i = 0; i < 16; ++i) lds2[eaddr(c, rowP2(sub, i))] = y[i];
        __syncthreads();
        #pragma unroll
        for (int i = 0; i < 16; ++i) y[i] = lds2[eaddr(c, rowP3(sub, i))];
        // P3: s=256,512,1,2
        pref(qb, tf4, 9,  sub); apply<4>(y, qa);
        pref(qa, tf4, 10, sub); apply<8>(y, qb);
        pref(qb, tf4, 11, sub); apply<1>(y, qa);
        pref(qa, tf4, 12, sub); apply<2>(y, qb);     // layer12 pref crosses T3
        // T3: wr P3 / rd P4
        __syncthreads();
        #pragma unroll
        for (int i = 0; i < 16; ++i) lds2[eaddr(c, rowP3(sub, i))] = y[i];
        __syncthreads();
        #pragma unroll
        for (int i = 0; i < 16; ++i) y[i] = lds2[eaddr(c, rowP4(sub, i))];
        // P4: s=4,8,16,32
        pref(qb, tf4, 13, sub); apply<1>(y, qa);
        pref(qa, tf4, 14, sub); apply<2>(y, qb);
        pref(qb, tf4, 15, sub); apply<4>(y, qa);
        pref(qa, tf4, 16, sub); apply<8>(y, qb);     // layer16 pref crosses T4
        // T4: wr P4 / rd P5
        __syncthreads();
        #pragma unroll
        for (int i = 0; i < 16; ++i) lds2[eaddr(c, rowP4(sub, i))] = y[i];
        __syncthreads();
        #pragma unroll
        for (int i = 0; i < 16; ++i) y[i] = lds2[eaddr(c, rowP5(sub, i))];
        // P5: s=64,128,256,512
        pref(qb, tf4, 17, sub); apply<1>(y, qa);
        pref(qa, tf4, 18, sub); apply<2>(y, qb);
        pref(qb, tf4, 19, sub); apply<4>(y, qa);
                                apply<8>(y, qb);
    } else {
        #pragma unroll
        for (int i = 0; i < 16; ++i)
            y[i] = Xp[rowP1(sub, i) * BATCH2];
        layer_notab<1,0,0>(y, ang + 0 * NANG, sub);
        layer_notab<2,0,1>(y, ang + 1 * NANG, sub);
        layer_notab<4,0,2>(y, ang + 2 * NANG, sub);
        layer_notab<8,0,3>(y, ang + 3 * NANG, sub);
        #pragma unroll
        for (int i = 0; i < 16; ++i) lds2[eaddr(c, rowP1(sub, i))] = y[i];
        __syncthreads();
        #pragma unroll
        for (int i = 0; i < 16; ++i) y[i] = lds2[eaddr(c, rowP2(sub, i))];
        layer_notab<1,1,4>(y, ang + 4 * NANG, sub);
        layer_notab<2,1,5>(y, ang + 5 * NANG, sub);
        layer_notab<4,1,6>(y, ang + 6 * NANG, sub);
        layer_notab<8,1,7>(y, ang + 7 * NANG, sub);
        __syncthreads();
        #pragma unroll
        for (int i = 0; i < 16; ++i) lds2[eaddr(c, rowP2(sub, i))] = y[i];
        __syncthreads();
        #pragma unroll
        for (int i = 0; i < 16; ++i) y[i] = lds2[eaddr(c, rowP3(sub, i))];
        layer_notab<4,2,8>(y, ang +  8 * NANG, sub);
        layer_notab<8,2,9>(y, ang +  9 * NANG, sub);
        layer_notab<1,2,0>(y, ang + 10 * NANG, sub);
        layer_notab<2,2,1>(y, ang + 11 * NANG, sub);
        __syncthreads();
        #pragma unroll
        for (int i = 0; i < 16; ++i) lds2[eaddr(c, rowP3(sub, i))] = y[i];
        __syncthreads();
        #pragma unroll
        for (int i = 0; i < 16; ++i) y[i] = lds2[eaddr(c, rowP4(sub, i))];
        layer_notab<1,3,2>(y, ang + 12 * NANG, sub);
        layer_notab<2,3,3>(y, ang + 13 * NANG, sub);
        layer_notab<4,3,4>(y, ang + 14 * NANG, sub);
        layer_notab<8,3,5>(y, ang + 15 * NANG, sub);
        __syncthreads();
        #pragma unroll
        for (int i = 0; i < 16; ++i) lds2[eaddr(c, rowP4(sub, i))] = y[i];
        __syncthreads();
        #pragma unroll
        for (int i = 0; i < 16; ++i) y[i] = lds2[eaddr(c, rowP5(sub, i))];
        layer_notab<1,4,6>(y, ang + 16 * NANG, sub);
        layer_notab<2,4,7>(y, ang + 17 * NANG, sub);
        layer_notab<4,4,8>(y, ang + 18 * NANG, sub);
        layer_notab<8,4,9>(y, ang + 19 * NANG, sub);
    }

    float2* Op = reinterpret_cast<float2*>(out) + col2;
    #pragma unroll
    for (int i = 0; i < 16; ++i)
        Op[rowP5(sub, i) * BATCH2] = y[i];
}

extern "C" void kernel_launch(void* const* d_in, const int* in_sizes, int n_in,
                              void* d_out, int out_size, void* d_ws, size_t ws_size,
                              hipStream_t stream) {
    (void)in_sizes; (void)n_in; (void)out_size;
    const float* X   = (const float*)d_in[0];
    const float* ang = (const float*)d_in[1];
    float* out = (float*)d_out;

    bool use_tab = (d_ws != nullptr) && (ws_size >= TAB_BYTES);
    if (use_tab) {
        float2* tab = (float2*)d_ws;
        build_tab_kernel<<<(TAB_ELEMS + 255) / 256, 256, 0, stream>>>(ang, tab);
        butterfly_kernel<true><<<512, 512, 0, stream>>>(X, ang, tab, out);
    } else {
        butterfly_kernel<false><<<512, 512, 0, stream>>>(X, ang, nullptr, out);
    }
}

// Round 10
// 37.037 us; speedup vs baseline: 1.0231x; 1.0231x over previous
//
#include <hip/hip_runtime.h>
#include <math.h>

// OrthogonalButterfly: X (1024 x 8192) fp32, 20 butterfly layers, stride 2^(l%10).
// R8 = 36.8us best: 512 thr = 8 f2cols x 64 subs, y=float2[16], LDS 64KB,
// 4-transpose/7-sync, involution swizzle. R9 (explicit prefetch) neutral.
// Floors: VALU ~8.5us, HBM ~8us, LDS ~4us -> ~20us is latency/convoy overhead:
// grid==capacity (2 blocks/CU, no refill), 8-wave barrier scope.
// R10: identical instruction mix, finer blocks: 256 thr = 4 f2cols x 64 subs,
// LDS 32KB, grid 1024. Barrier scope 4 waves; 5 resident slots vs 4 avg ->
// refill slack; cap 20 waves/CU. Global segments 32B (L2 coalesces, per R6/R7
// FETCH/WRITE evidence). Row maps/table/swizzle byte-identical to R8.
//
// Phase row maps (sub in [0,64), i in [0,16)):
//   P1: r = sub<<4 | i                          layers s=1,2,4,8     (SL=1,2,4,8)
//   P2: r = (sub&15) | i<<4 | (sub>>4)<<8       layers s=16..128     (SL=1,2,4,8)
//   P3: r = (i&3) | sub<<2 | (i>>2)<<8          layers s=256,512,1,2 (SL=4,8,1,2)
//   P4: r = (sub&3) | (i&3)<<2 | ((i>>2)&3)<<4 | (sub>>2)<<6
//                                               layers s=4..32       (SL=1,2,4,8)
//   P5: r = sub | (i&3)<<6 | (i>>2)<<8          layers s=64..512     (SL=1,2,4,8)

#define NROW   1024
#define BATCH  8192
#define BATCH2 (BATCH / 2)
#define DEPTH  20
#define NANG   512
#define TAB_ELEMS (DEPTH * NANG)
#define TAB_BYTES ((size_t)TAB_ELEMS * 8)

__device__ __host__ __forceinline__ int rowP1(int sub, int i){ return (sub<<4)|i; }
__device__ __host__ __forceinline__ int rowP2(int sub, int i){ return (sub&15) | (i<<4) | ((sub>>4)<<8); }
__device__ __host__ __forceinline__ int rowP3(int sub, int i){ return (i&3) | (sub<<2) | ((i>>2)<<8); }
__device__ __host__ __forceinline__ int rowP4(int sub, int i){ return (sub&3) | ((i&3)<<2) | (((i>>2)&3)<<4) | ((sub>>2)<<6); }
__device__ __host__ __forceinline__ int rowP5(int sub, int i){ return sub | ((i&3)<<6) | ((i>>2)<<8); }

// ---------------- angle table build (identical to R6-R9, verified) ----------------
__global__ void build_tab_kernel(const float* __restrict__ ang,
                                 float2* __restrict__ tab) {
    int idx = blockIdx.x * blockDim.x + threadIdx.x;
    if (idx >= TAB_ELEMS) return;
    int l = idx >> 9;
    int slot = idx & (NANG - 1);
    int sub = slot >> 3, p = slot & 7;
    int sp = l % 10;
    int SL, ph;
    if (l < 4)       { ph = 0; SL = 1 << l; }
    else if (l < 8)  { ph = 1; SL = 1 << (l - 4); }
    else if (l < 12) { ph = 2; SL = (l == 8) ? 4 : (l == 9) ? 8 : (l == 10) ? 1 : 2; }
    else if (l < 16) { ph = 3; SL = 1 << (l - 12); }
    else             { ph = 4; SL = 1 << (l - 16); }
    int i0 = 2 * (p / SL) * SL + p % SL;
    int r;
    if (ph == 0)      r = rowP1(sub, i0);
    else if (ph == 1) r = rowP2(sub, i0);
    else if (ph == 2) r = rowP3(sub, i0);
    else if (ph == 3) r = rowP4(sub, i0);
    else              r = rowP5(sub, i0);
    int s = 1 << sp;
    int a = ((r >> (sp + 1)) << sp) | (r & (s - 1));
    float th = ang[l * NANG + a];
    float sv, cv;
    sincosf(th, &sv, &cv);
    tab[idx] = make_float2(cv, sv);
}

// ---------------- main kernel ----------------
__device__ __forceinline__ void rot2(float2& a, float2& b, float cv, float sv) {
    float2 x0 = a, x1 = b;
    a.x = cv * x0.x + sv * x1.x;  b.x = cv * x1.x - sv * x0.x;
    a.y = cv * x0.y + sv * x1.y;  b.y = cv * x1.y - sv * x0.y;
}

// One layer on 16 float2 rows, local pair-stride SL. Table slice = 4 float4
// at tl + 8*sub (8 cos/sin pairs, shared by the 4 c-lanes -> broadcast).
template<int SL>
__device__ __forceinline__ void layer_tab(float2 y[16],
                                          const float2* __restrict__ tl,
                                          int sub) {
    const float4* q4 = reinterpret_cast<const float4*>(tl + 8 * sub);
    #pragma unroll
    for (int v = 0; v < 4; ++v) {
        float4 q = q4[v];
        int p0 = 2 * v, p1 = 2 * v + 1;
        int a0 = 2 * (p0 / SL) * SL + p0 % SL;   // constant-folds
        int a1 = 2 * (p1 / SL) * SL + p1 % SL;
        rot2(y[a0], y[a0 + SL], q.x, q.y);
        rot2(y[a1], y[a1 + SL], q.z, q.w);
    }
}

// Fallback without workspace: inline sincos (angles shared by the 2 cols).
template<int SL, int PH, int SP>
__device__ __forceinline__ void layer_notab(float2 y[16],
                                            const float* __restrict__ angL,
                                            int sub) {
    #pragma unroll
    for (int p = 0; p < 8; ++p) {
        int i0 = 2 * (p / SL) * SL + p % SL;
        int r;
        if (PH == 0)      r = rowP1(sub, i0);
        else if (PH == 1) r = rowP2(sub, i0);
        else if (PH == 2) r = rowP3(sub, i0);
        else if (PH == 3) r = rowP4(sub, i0);
        else              r = rowP5(sub, i0);
        int a = ((r >> (SP + 1)) << SP) | (r & ((1 << SP) - 1));
        float th = angL[a];
        float sv, cv;
        __sincosf(th, &sv, &cv);
        rot2(y[i0], y[i0 + SL], cv, sv);
    }
}

// LDS element address for (float2-col c, row r). sigma involution pushes sub
// bits into the bank index on all phase maps; c<<1 decorrelates columns.
// Verified: 16 distinct bank-pair indices per wave on all 5 phase maps.
__device__ __forceinline__ int eaddr(int c, int r) {
    return (c << 10) | ((r ^ ((r >> 4) & 15)) ^ (c << 1));
}

template<bool USE_TAB>
__global__ __launch_bounds__(256) void butterfly_kernel(
        const float* __restrict__ X, const float* __restrict__ ang,
        const float2* __restrict__ tab, float* __restrict__ out) {
    __shared__ float2 lds2[4 * 1024];    // 32 KB -> 5 resident blocks/CU
    int t = threadIdx.x;
    int c = t & 3;                       // float2-column within block
    int sub = t >> 2;                    // [0,64)
    int bid = blockIdx.x;
    int L = ((bid & 7) << 7) | (bid >> 3);   // XCD-aware, bijective (1024 = 8*128)
    int col2 = (L << 2) + c;             // float2-col in [0,4096)

    float2 y[16];
    const float2* Xp = reinterpret_cast<const float2*>(X) + col2;
    #pragma unroll
    for (int i = 0; i < 16; ++i)
        y[i] = Xp[rowP1(sub, i) * BATCH2];

    if (USE_TAB) {
        layer_tab<1>(y, tab + 0 * NANG, sub);    // s=1
        layer_tab<2>(y, tab + 1 * NANG, sub);    // s=2
        layer_tab<4>(y, tab + 2 * NANG, sub);    // s=4
        layer_tab<8>(y, tab + 3 * NANG, sub);    // s=8
    } else {
        layer_notab<1,0,0>(y, ang + 0 * NANG, sub);
        layer_notab<2,0,1>(y, ang + 1 * NANG, sub);
        layer_notab<4,0,2>(y, ang + 2 * NANG, sub);
        layer_notab<8,0,3>(y, ang + 3 * NANG, sub);
    }
    // T1: wr P1 / rd P2
    #pragma unroll
    for (int i = 0; i < 16; ++i) lds2[eaddr(c, rowP1(sub, i))] = y[i];
    __syncthreads();
    #pragma unroll
    for (int i = 0; i < 16; ++i) y[i] = lds2[eaddr(c, rowP2(sub, i))];

    if (USE_TAB) {
        layer_tab<1>(y, tab + 4 * NANG, sub);    // s=16
        layer_tab<2>(y, tab + 5 * NANG, sub);    // s=32
        layer_tab<4>(y, tab + 6 * NANG, sub);    // s=64
        layer_tab<8>(y, tab + 7 * NANG, sub);    // s=128
    } else {
        layer_notab<1,1,4>(y, ang + 4 * NANG, sub);
        layer_notab<2,1,5>(y, ang + 5 * NANG, sub);
        layer_notab<4,1,6>(y, ang + 6 * NANG, sub);
        layer_notab<8,1,7>(y, ang + 7 * NANG, sub);
    }
    // T2: wr P2 / rd P3
    __syncthreads();
    #pragma unroll
    for (int i = 0; i < 16; ++i) lds2[eaddr(c, rowP2(sub, i))] = y[i];
    __syncthreads();
    #pragma unroll
    for (int i = 0; i < 16; ++i) y[i] = lds2[eaddr(c, rowP3(sub, i))];

    if (USE_TAB) {
        layer_tab<4>(y, tab +  8 * NANG, sub);   // s=256
        layer_tab<8>(y, tab +  9 * NANG, sub);   // s=512
        layer_tab<1>(y, tab + 10 * NANG, sub);   // s=1
        layer_tab<2>(y, tab + 11 * NANG, sub);   // s=2
    } else {
        layer_notab<4,2,8>(y, ang +  8 * NANG, sub);
        layer_notab<8,2,9>(y, ang +  9 * NANG, sub);
        layer_notab<1,2,0>(y, ang + 10 * NANG, sub);
        layer_notab<2,2,1>(y, ang + 11 * NANG, sub);
    }
    // T3: wr P3 / rd P4
    __syncthreads();
    #pragma unroll
    for (int i = 0; i < 16; ++i) lds2[eaddr(c, rowP3(sub, i))] = y[i];
    __syncthreads();
    #pragma unroll
    for (int i = 0; i < 16; ++i) y[i] = lds2[eaddr(c, rowP4(sub, i))];

    if (USE_TAB) {
        layer_tab<1>(y, tab + 12 * NANG, sub);   // s=4
        layer_tab<2>(y, tab + 13 * NANG, sub);   // s=8
        layer_tab<4>(y, tab + 14 * NANG, sub);   // s=16
        layer_tab<8>(y, tab + 15 * NANG, sub);   // s=32
    } else {
        layer_notab<1,3,2>(y, ang + 12 * NANG, sub);
        layer_notab<2,3,3>(y, ang + 13 * NANG, sub);
        layer_notab<4,3,4>(y, ang + 14 * NANG, sub);
        layer_notab<8,3,5>(y, ang + 15 * NANG, sub);
    }
    // T4: wr P4 / rd P5
    __syncthreads();
    #pragma unroll
    for (int i = 0; i < 16; ++i) lds2[eaddr(c, rowP4(sub, i))] = y[i];
    __syncthreads();
    #pragma unroll
    for (int i = 0; i < 16; ++i) y[i] = lds2[eaddr(c, rowP5(sub, i))];

    if (USE_TAB) {
        layer_tab<1>(y, tab + 16 * NANG, sub);   // s=64
        layer_tab<2>(y, tab + 17 * NANG, sub);   // s=128
        layer_tab<4>(y, tab + 18 * NANG, sub);   // s=256
        layer_tab<8>(y, tab + 19 * NANG, sub);   // s=512
    } else {
        layer_notab<1,4,6>(y, ang + 16 * NANG, sub);
        layer_notab<2,4,7>(y, ang + 17 * NANG, sub);
        layer_notab<4,4,8>(y, ang + 18 * NANG, sub);
        layer_notab<8,4,9>(y, ang + 19 * NANG, sub);
    }

    float2* Op = reinterpret_cast<float2*>(out) + col2;
    #pragma unroll
    for (int i = 0; i < 16; ++i)
        Op[rowP5(sub, i) * BATCH2] = y[i];
}

extern "C" void kernel_launch(void* const* d_in, const int* in_sizes, int n_in,
                              void* d_out, int out_size, void* d_ws, size_t ws_size,
                              hipStream_t stream) {
    (void)in_sizes; (void)n_in; (void)out_size;
    const float* X   = (const float*)d_in[0];
    const float* ang = (const float*)d_in[1];
    float* out = (float*)d_out;

    bool use_tab = (d_ws != nullptr) && (ws_size >= TAB_BYTES);
    if (use_tab) {
        float2* tab = (float2*)d_ws;
        build_tab_kernel<<<(TAB_ELEMS + 255) / 256, 256, 0, stream>>>(ang, tab);
        butterfly_kernel<true><<<1024, 256, 0, stream>>>(X, ang, tab, out);
    } else {
        butterfly_kernel<false><<<1024, 256, 0, stream>>>(X, ang, nullptr, out);
    }
}

// Round 11
// 32.748 us; speedup vs baseline: 1.1571x; 1.1310x over previous
//
#include <hip/hip_runtime.h>
#include <math.h>

// OrthogonalButterfly: X (1024 x 8192) fp32, 20 butterfly layers, stride 2^(l%10).
// R8 = 36.8us best. R9 (prefetch) / R10 (finer blocks) neutral -> plateau is
// VALU-issue-bound: rotations = 1280 scalar VALU ops/thread (~20us/CU issue).
// R11: packed fp32. rot on ext_vector float2 via __builtin_elementwise_fma ->
// v_pk_fma_f32 / v_pk_mul_f32: 4 pk instr per pair instead of 8 scalar,
// halving rotation issue. Geometry/schedule/table/swizzle byte-identical R8.
//
// Phase row maps (sub in [0,64), i in [0,16)):
//   P1: r = sub<<4 | i                          layers s=1,2,4,8     (SL=1,2,4,8)
//   P2: r = (sub&15) | i<<4 | (sub>>4)<<8       layers s=16..128     (SL=1,2,4,8)
//   P3: r = (i&3) | sub<<2 | (i>>2)<<8          layers s=256,512,1,2 (SL=4,8,1,2)
//   P4: r = (sub&3) | (i&3)<<2 | ((i>>2)&3)<<4 | (sub>>2)<<6
//                                               layers s=4..32       (SL=1,2,4,8)
//   P5: r = sub | (i&3)<<6 | (i>>2)<<8          layers s=64..512     (SL=1,2,4,8)

#define NROW   1024
#define BATCH  8192
#define BATCH2 (BATCH / 2)
#define DEPTH  20
#define NANG   512
#define TAB_ELEMS (DEPTH * NANG)
#define TAB_BYTES ((size_t)TAB_ELEMS * 8)

typedef float v2f __attribute__((ext_vector_type(2)));

__device__ __host__ __forceinline__ int rowP1(int sub, int i){ return (sub<<4)|i; }
__device__ __host__ __forceinline__ int rowP2(int sub, int i){ return (sub&15) | (i<<4) | ((sub>>4)<<8); }
__device__ __host__ __forceinline__ int rowP3(int sub, int i){ return (i&3) | (sub<<2) | ((i>>2)<<8); }
__device__ __host__ __forceinline__ int rowP4(int sub, int i){ return (sub&3) | ((i&3)<<2) | (((i>>2)&3)<<4) | ((sub>>2)<<6); }
__device__ __host__ __forceinline__ int rowP5(int sub, int i){ return sub | ((i&3)<<6) | ((i>>2)<<8); }

// ---------------- angle table build (identical to R6-R10, verified) ----------------
__global__ void build_tab_kernel(const float* __restrict__ ang,
                                 float2* __restrict__ tab) {
    int idx = blockIdx.x * blockDim.x + threadIdx.x;
    if (idx >= TAB_ELEMS) return;
    int l = idx >> 9;
    int slot = idx & (NANG - 1);
    int sub = slot >> 3, p = slot & 7;
    int sp = l % 10;
    int SL, ph;
    if (l < 4)       { ph = 0; SL = 1 << l; }
    else if (l < 8)  { ph = 1; SL = 1 << (l - 4); }
    else if (l < 12) { ph = 2; SL = (l == 8) ? 4 : (l == 9) ? 8 : (l == 10) ? 1 : 2; }
    else if (l < 16) { ph = 3; SL = 1 << (l - 12); }
    else             { ph = 4; SL = 1 << (l - 16); }
    int i0 = 2 * (p / SL) * SL + p % SL;
    int r;
    if (ph == 0)      r = rowP1(sub, i0);
    else if (ph == 1) r = rowP2(sub, i0);
    else if (ph == 2) r = rowP3(sub, i0);
    else if (ph == 3) r = rowP4(sub, i0);
    else              r = rowP5(sub, i0);
    int s = 1 << sp;
    int a = ((r >> (sp + 1)) << sp) | (r & (s - 1));
    float th = ang[l * NANG + a];
    float sv, cv;
    sincosf(th, &sv, &cv);
    tab[idx] = make_float2(cv, sv);
}

// ---------------- main kernel ----------------
// Packed rotation: both lanes of the float2 column-pair share (c,s).
// a' = c*x0 + s*x1 = pk_fma(c, x0, pk_mul(s, x1))
// b' = c*x1 - s*x0 = pk_fma(-s, x0, pk_mul(c, x1))   (neg folds into modifier)
__device__ __forceinline__ void rotp(v2f& a, v2f& b, float cv, float sv) {
    v2f c = {cv, cv}, s = {sv, sv};
    v2f x0 = a, x1 = b;
    a = __builtin_elementwise_fma(c, x0, s * x1);
    b = __builtin_elementwise_fma(-s, x0, c * x1);
}

// One layer on 16 v2f rows, local pair-stride SL. Table slice = 4 float4
// at tl + 8*sub (8 cos/sin pairs, shared by the 8 c-lanes -> broadcast).
template<int SL>
__device__ __forceinline__ void layer_tab(v2f y[16],
                                          const float2* __restrict__ tl,
                                          int sub) {
    const float4* q4 = reinterpret_cast<const float4*>(tl + 8 * sub);
    #pragma unroll
    for (int v = 0; v < 4; ++v) {
        float4 q = q4[v];
        int p0 = 2 * v, p1 = 2 * v + 1;
        int a0 = 2 * (p0 / SL) * SL + p0 % SL;   // constant-folds
        int a1 = 2 * (p1 / SL) * SL + p1 % SL;
        rotp(y[a0], y[a0 + SL], q.x, q.y);
        rotp(y[a1], y[a1 + SL], q.z, q.w);
    }
}

// Fallback without workspace: inline sincos (angles shared by the 2 cols).
template<int SL, int PH, int SP>
__device__ __forceinline__ void layer_notab(v2f y[16],
                                            const float* __restrict__ angL,
                                            int sub) {
    #pragma unroll
    for (int p = 0; p < 8; ++p) {
        int i0 = 2 * (p / SL) * SL + p % SL;
        int r;
        if (PH == 0)      r = rowP1(sub, i0);
        else if (PH == 1) r = rowP2(sub, i0);
        else if (PH == 2) r = rowP3(sub, i0);
        else if (PH == 3) r = rowP4(sub, i0);
        else              r = rowP5(sub, i0);
        int a = ((r >> (SP + 1)) << SP) | (r & ((1 << SP) - 1));
        float th = angL[a];
        float sv, cv;
        __sincosf(th, &sv, &cv);
        rotp(y[i0], y[i0 + SL], cv, sv);
    }
}

// LDS element address for (float2-col c, row r). sigma involution pushes sub
// bits into the bank index on all phase maps; c<<1 decorrelates columns.
__device__ __forceinline__ int eaddr(int c, int r) {
    return (c << 10) | ((r ^ ((r >> 4) & 15)) ^ (c << 1));
}

template<bool USE_TAB>
__global__ __launch_bounds__(512) void butterfly_kernel(
        const float* __restrict__ X, const float* __restrict__ ang,
        const float2* __restrict__ tab, float* __restrict__ out) {
    __shared__ v2f lds2[8 * 1024];       // 64 KB -> 2 blocks/CU
    int t = threadIdx.x;
    int c = t & 7;                       // float2-column within block
    int sub = t >> 3;                    // [0,64)
    int bid = blockIdx.x;
    int L = ((bid & 7) << 6) | (bid >> 3);   // XCD-aware, bijective (512 = 8*64)
    int col2 = (L << 3) + c;             // float2-col in [0,4096)

    v2f y[16];
    const v2f* Xp = reinterpret_cast<const v2f*>(X) + col2;
    #pragma unroll
    for (int i = 0; i < 16; ++i)
        y[i] = Xp[rowP1(sub, i) * BATCH2];

    if (USE_TAB) {
        layer_tab<1>(y, tab + 0 * NANG, sub);    // s=1
        layer_tab<2>(y, tab + 1 * NANG, sub);    // s=2
        layer_tab<4>(y, tab + 2 * NANG, sub);    // s=4
        layer_tab<8>(y, tab + 3 * NANG, sub);    // s=8
    } else {
        layer_notab<1,0,0>(y, ang + 0 * NANG, sub);
        layer_notab<2,0,1>(y, ang + 1 * NANG, sub);
        layer_notab<4,0,2>(y, ang + 2 * NANG, sub);
        layer_notab<8,0,3>(y, ang + 3 * NANG, sub);
    }
    // T1: wr P1 / rd P2
    #pragma unroll
    for (int i = 0; i < 16; ++i) lds2[eaddr(c, rowP1(sub, i))] = y[i];
    __syncthreads();
    #pragma unroll
    for (int i = 0; i < 16; ++i) y[i] = lds2[eaddr(c, rowP2(sub, i))];

    if (USE_TAB) {
        layer_tab<1>(y, tab + 4 * NANG, sub);    // s=16
        layer_tab<2>(y, tab + 5 * NANG, sub);    // s=32
        layer_tab<4>(y, tab + 6 * NANG, sub);    // s=64
        layer_tab<8>(y, tab + 7 * NANG, sub);    // s=128
    } else {
        layer_notab<1,1,4>(y, ang + 4 * NANG, sub);
        layer_notab<2,1,5>(y, ang + 5 * NANG, sub);
        layer_notab<4,1,6>(y, ang + 6 * NANG, sub);
        layer_notab<8,1,7>(y, ang + 7 * NANG, sub);
    }
    // T2: wr P2 / rd P3
    __syncthreads();
    #pragma unroll
    for (int i = 0; i < 16; ++i) lds2[eaddr(c, rowP2(sub, i))] = y[i];
    __syncthreads();
    #pragma unroll
    for (int i = 0; i < 16; ++i) y[i] = lds2[eaddr(c, rowP3(sub, i))];

    if (USE_TAB) {
        layer_tab<4>(y, tab +  8 * NANG, sub);   // s=256
        layer_tab<8>(y, tab +  9 * NANG, sub);   // s=512
        layer_tab<1>(y, tab + 10 * NANG, sub);   // s=1
        layer_tab<2>(y, tab + 11 * NANG, sub);   // s=2
    } else {
        layer_notab<4,2,8>(y, ang +  8 * NANG, sub);
        layer_notab<8,2,9>(y, ang +  9 * NANG, sub);
        layer_notab<1,2,0>(y, ang + 10 * NANG, sub);
        layer_notab<2,2,1>(y, ang + 11 * NANG, sub);
    }
    // T3: wr P3 / rd P4
    __syncthreads();
    #pragma unroll
    for (int i = 0; i < 16; ++i) lds2[eaddr(c, rowP3(sub, i))] = y[i];
    __syncthreads();
    #pragma unroll
    for (int i = 0; i < 16; ++i) y[i] = lds2[eaddr(c, rowP4(sub, i))];

    if (USE_TAB) {
        layer_tab<1>(y, tab + 12 * NANG, sub);   // s=4
        layer_tab<2>(y, tab + 13 * NANG, sub);   // s=8
        layer_tab<4>(y, tab + 14 * NANG, sub);   // s=16
        layer_tab<8>(y, tab + 15 * NANG, sub);   // s=32
    } else {
        layer_notab<1,3,2>(y, ang + 12 * NANG, sub);
        layer_notab<2,3,3>(y, ang + 13 * NANG, sub);
        layer_notab<4,3,4>(y, ang + 14 * NANG, sub);
        layer_notab<8,3,5>(y, ang + 15 * NANG, sub);
    }
    // T4: wr P4 / rd P5
    __syncthreads();
    #pragma unroll
    for (int i = 0; i < 16; ++i) lds2[eaddr(c, rowP4(sub, i))] = y[i];
    __syncthreads();
    #pragma unroll
    for (int i = 0; i < 16; ++i) y[i] = lds2[eaddr(c, rowP5(sub, i))];

    if (USE_TAB) {
        layer_tab<1>(y, tab + 16 * NANG, sub);   // s=64
        layer_tab<2>(y, tab + 17 * NANG, sub);   // s=128
        layer_tab<4>(y, tab + 18 * NANG, sub);   // s=256
        layer_tab<8>(y, tab + 19 * NANG, sub);   // s=512
    } else {
        layer_notab<1,4,6>(y, ang + 16 * NANG, sub);
        layer_notab<2,4,7>(y, ang + 17 * NANG, sub);
        layer_notab<4,4,8>(y, ang + 18 * NANG, sub);
        layer_notab<8,4,9>(y, ang + 19 * NANG, sub);
    }

    v2f* Op = reinterpret_cast<v2f*>(out) + col2;
    #pragma unroll
    for (int i = 0; i < 16; ++i)
        Op[rowP5(sub, i) * BATCH2] = y[i];
}

extern "C" void kernel_launch(void* const* d_in, const int* in_sizes, int n_in,
                              void* d_out, int out_size, void* d_ws, size_t ws_size,
                              hipStream_t stream) {
    (void)in_sizes; (void)n_in; (void)out_size;
    const float* X   = (const float*)d_in[0];
    const float* ang = (const float*)d_in[1];
    float* out = (float*)d_out;

    bool use_tab = (d_ws != nullptr) && (ws_size >= TAB_BYTES);
    if (use_tab) {
        float2* tab = (float2*)d_ws;
        build_tab_kernel<<<(TAB_ELEMS + 255) / 256, 256, 0, stream>>>(ang, tab);
        butterfly_kernel<true><<<512, 512, 0, stream>>>(X, ang, tab, out);
    } else {
        butterfly_kernel<false><<<512, 512, 0, stream>>>(X, ang, nullptr, out);
    }
}